// Round 13
// baseline (1579.011 us; speedup 1.0000x reference)
//
#include <hip/hip_runtime.h>
#include <math.h>

#define NRES 8192
#define NPER 2048
#define KNB  30
#define NEDGE (NRES*KNB)

__device__ __forceinline__ float siluf(float x){ return x / (1.0f + __expf(-x)); }

// ---------------- K0: backbone features + ca pack ----------------
__global__ void k_bbfeat(const float* __restrict__ bb, float* __restrict__ bbf,
                         float4* __restrict__ ca){
  int n = blockIdx.x*256 + threadIdx.x;
  if(n >= NRES) return;
  const float* r = bb + n*12;
  float cax=r[3], cay=r[4], caz=r[5];
  ca[n] = make_float4(cax,cay,caz, cax*cax+cay*cay+caz*caz);
  float vx[7],vy[7],vz[7];
  for(int a=0;a<4;a++){ vx[a]=r[a*3]-cax; vy[a]=r[a*3+1]-cay; vz[a]=r[a*3+2]-caz; }
  if(n<NRES-1){
    float dx=bb[(n+1)*12+3]-cax, dy=bb[(n+1)*12+4]-cay, dz=bb[(n+1)*12+5]-caz;
    float s=rsqrtf(dx*dx+dy*dy+dz*dz+1e-8f);
    vx[4]=dx*s; vy[4]=dy*s; vz[4]=dz*s;
  } else { vx[4]=0.f; vy[4]=0.f; vz[4]=0.f; }
  if(n>0){
    float dx=bb[(n-1)*12+3]-cax, dy=bb[(n-1)*12+4]-cay, dz=bb[(n-1)*12+5]-caz;
    float s=rsqrtf(dx*dx+dy*dy+dz*dz+1e-8f);
    vx[5]=dx*s; vy[5]=dy*s; vz[5]=dz*s;
  } else { vx[5]=0.f; vy[5]=0.f; vz[5]=0.f; }
  {
    float bx=cax-r[0], by=cay-r[1], bz=caz-r[2];
    float cx=r[6]-cax, cy=r[7]-cay, cz=r[8]-caz;
    float axx=by*cz-bz*cy, ayy=bz*cx-bx*cz, azz=bx*cy-by*cx;
    vx[6]=-0.58273431f*axx+0.56802827f*bx-0.54067466f*cx;
    vy[6]=-0.58273431f*ayy+0.56802827f*by-0.54067466f*cy;
    vz[6]=-0.58273431f*azz+0.56802827f*bz-0.54067466f*cz;
  }
  float cD[3], sD[3];
  for(int t=0;t<3;t++){
    cD[t]=1.0f; sD[t]=0.0f;
    int f=3*n+t-1;
    if(f>=0 && f<3*NRES-3){
      float X[4][3];
      for(int q=0;q<4;q++){
        int m=f+q, rr=m/3, aa=m-rr*3;
        X[q][0]=bb[rr*12+aa*3]; X[q][1]=bb[rr*12+aa*3+1]; X[q][2]=bb[rr*12+aa*3+2];
      }
      float u2x=X[1][0]-X[0][0], u2y=X[1][1]-X[0][1], u2z=X[1][2]-X[0][2];
      float u1x=X[2][0]-X[1][0], u1y=X[2][1]-X[1][1], u1z=X[2][2]-X[1][2];
      float u0x=X[3][0]-X[2][0], u0y=X[3][1]-X[2][1], u0z=X[3][2]-X[2][2];
      float s2=rsqrtf(u2x*u2x+u2y*u2y+u2z*u2z+1e-8f); u2x*=s2; u2y*=s2; u2z*=s2;
      float s1=rsqrtf(u1x*u1x+u1y*u1y+u1z*u1z+1e-8f); u1x*=s1; u1y*=s1; u1z*=s1;
      float s0=rsqrtf(u0x*u0x+u0y*u0y+u0z*u0z+1e-8f); u0x*=s0; u0y*=s0; u0z*=s0;
      float n2x=u2y*u1z-u2z*u1y, n2y=u2z*u1x-u2x*u1z, n2z=u2x*u1y-u2y*u1x;
      float nn2=rsqrtf(n2x*n2x+n2y*n2y+n2z*n2z+1e-8f); n2x*=nn2; n2y*=nn2; n2z*=nn2;
      float n1x=u1y*u0z-u1z*u0y, n1y=u1z*u0x-u1x*u0z, n1z=u1x*u0y-u1y*u0x;
      float nn1=rsqrtf(n1x*n1x+n1y*n1y+n1z*n1z+1e-8f); n1x*=nn1; n1y*=nn1; n1z*=nn1;
      float dotn = n2x*n1x+n2y*n1y+n2z*n1z;
      float cosD = fminf(fmaxf(dotn, -1.0f+1e-6f), 1.0f-1e-6f);
      float sg = u2x*n1x+u2y*n1y+u2z*n1z;
      if(sg==0.0f){ cD[t]=1.0f; sD[t]=0.0f; }
      else {
        float sgn = (sg>0.0f)?1.0f:-1.0f;
        cD[t]=cosD;
        sD[t]=sgn*sqrtf(fmaxf(1.0f-cosD*cosD,0.0f));
      }
    }
  }
  float* o = bbf + n*28;
  o[0]=cD[0]; o[1]=cD[1]; o[2]=cD[2]; o[3]=sD[0]; o[4]=sD[1]; o[5]=sD[2]; o[6]=0.f;
  for(int c=0;c<7;c++){ o[7+c]=vx[c]; o[14+c]=vy[c]; o[21+c]=vz[c]; }
}

// ---------------- K1: kNN — 8 queries/block, group-minima selection (round-7 validated) ----------------
__global__ __launch_bounds__(512) void k_knn(const float4* __restrict__ ca, int* __restrict__ nbr){
  __shared__ float sx[NPER], sy[NPER], sz[NPER], sq[NPER];
  int wave = threadIdx.x>>6;      // 0..7
  int lane = threadIdx.x&63;
  int i = blockIdx.x*8 + wave;    // 8 | 2048 -> whole block same batch
  int batch = i / NPER;
  int base = batch*NPER;
  for(int t=threadIdx.x; t<NPER; t+=512){
    float4 c = ca[base+t];
    sx[t]=c.x; sy[t]=c.y; sz[t]=c.z; sq[t]=c.w;
  }
  __syncthreads();
  int il = i - base;
  float xi=sx[il], yi=sy[il], zi=sz[il], si=sq[il];
  float vals[32];
  float gm[4]; int ga[4];
  #pragma unroll
  for(int grp=0;grp<4;grp++){ gm[grp]=1e30f; ga[grp]=grp*8; }
  #pragma unroll
  for(int t=0;t<32;t++){
    int j = t*64 + lane;
    float d2 = si + sq[j] - 2.0f*(xi*sx[j]+yi*sy[j]+zi*sz[j]);
    if(j==il) d2 = 1e30f;
    vals[t]=d2;
    int grp = t>>3;
    if(d2 < gm[grp]){ gm[grp]=d2; ga[grp]=t; }
  }
  float lmin = gm[0]; int larg = ga[0];
  if(gm[1]<lmin){ lmin=gm[1]; larg=ga[1]; }
  if(gm[2]<lmin){ lmin=gm[2]; larg=ga[2]; }
  if(gm[3]<lmin){ lmin=gm[3]; larg=ga[3]; }
  for(int it=0; it<KNB; it++){
    float v = lmin; int jg = larg*64 + lane;
    #pragma unroll
    for(int off=32; off>0; off>>=1){
      float vo = __shfl_xor(v, off, 64);
      int   jo = __shfl_xor(jg, off, 64);
      if(vo < v || (vo==v && jo<jg)){ v=vo; jg=jo; }   // (d2, j) lexicographic
    }
    if(lane==0) nbr[i*KNB+it] = base + jg;
    if((jg&63)==lane){
      int wt = jg>>6;
      int grp = wt>>3;
      #pragma unroll
      for(int g2=0; g2<4; g2++){
        if(grp==g2){
          #pragma unroll
          for(int q=0;q<8;q++) if(g2*8+q==wt) vals[g2*8+q]=1e30f;
          float m=1e30f; int a=g2*8;
          #pragma unroll
          for(int q=0;q<8;q++){ if(vals[g2*8+q]<m){ m=vals[g2*8+q]; a=g2*8+q; } }
          gm[g2]=m; ga[g2]=a;
        }
      }
      lmin=gm[0]; larg=ga[0];
      if(gm[1]<lmin){ lmin=gm[1]; larg=ga[1]; }
      if(gm[2]<lmin){ lmin=gm[2]; larg=ga[2]; }
      if(gm[3]<lmin){ lmin=gm[3]; larg=ga[3]; }
    }
  }
}

// ---------------- K2: edge features ef (N,k,32) = [rbf16, cos8, sin8] ----------------
__global__ void k_edgefeat(const float4* __restrict__ ca, const int* __restrict__ nbr,
                           float* __restrict__ ef){
  int e = blockIdx.x*256 + threadIdx.x;
  if(e >= NEDGE) return;
  int n = e/KNB;
  int j = nbr[e];
  float4 cn = ca[n], cj = ca[j];
  float dx=cn.x-cj.x, dy=cn.y-cj.y, dz=cn.z-cj.z;
  float dist = sqrtf(dx*dx+dy*dy+dz*dz + 1e-12f);
  float f[32];
  #pragma unroll
  for(int m=0;m<16;m++){
    float mu = (20.0f/15.0f)*(float)m;
    float t = (dist-mu)*(1.0f/1.25f);
    f[m] = __expf(-t*t);
  }
  float didx = (float)(j - n);
  #pragma unroll
  for(int m=0;m<8;m++){
    float freq = __expf(-1.1512925465f*(float)m);  // 10000^(-m/8)
    float ang = didx*freq;
    f[16+m]=cosf(ang); f[24+m]=sinf(ang);
  }
  float4* o4 = (float4*)(ef + (size_t)e*32);
  #pragma unroll
  for(int q=0;q<8;q++) o4[q] = make_float4(f[q*4],f[q*4+1],f[q*4+2],f[q*4+3]);
}

// ---------------- K3: norm_so3 (latent only) ----------------
__global__ void k_norm(const float* __restrict__ in, float* __restrict__ out,
                       const float* __restrict__ g0, const float* __restrict__ b0,
                       const float* __restrict__ g1){
  int tid = blockIdx.x*256 + threadIdx.x;
  int n = tid >> 5, lane = tid & 31;
  if(n >= NRES) return;
  const float* xn = in + n*128;
  float x0 = xn[lane];
  float s = x0, s2 = x0*x0;
  for(int off=16; off>0; off>>=1){ s += __shfl_xor(s, off, 32); s2 += __shfl_xor(s2, off, 32); }
  float mu = s*(1.0f/32.0f);
  float var = s2*(1.0f/32.0f) - mu*mu;
  float y0 = (x0-mu)*rsqrtf(var+1e-6f)*g0[lane] + b0[lane];
  float v1 = xn[32+lane], v2 = xn[64+lane], v3 = xn[96+lane];
  float ss = v1*v1+v2*v2+v3*v3;
  for(int off=16; off>0; off>>=1){ ss += __shfl_xor(ss, off, 32); }
  float sc = rsqrtf(ss*(1.0f/96.0f) + 1e-6f);
  float g = g1[lane];
  out[n*128+lane]     = y0;
  out[n*128+32+lane]  = v1*sc*g;
  out[n*128+64+lane]  = v2*sc*g;
  out[n*128+96+lane]  = v3*sc*g;
}

// helper: load 32 floats into a register array (callers index with constants only)
__device__ __forceinline__ void load32(float* __restrict__ f, const float* __restrict__ src){
  const float4* s4 = (const float4*)src;
  #pragma unroll
  for(int q=0;q<8;q++){
    float4 v = s4[q];
    f[q*4+0]=v.x; f[q*4+1]=v.y; f[q*4+2]=v.z; f[q*4+3]=v.w;
  }
}

// ---------------- K4a: init radial MLPs, lane-per-edge, all-register ----------------
__global__ __launch_bounds__(256,4) void k_rad(const float* __restrict__ ef,
                     const float* __restrict__ bbw1, const float* __restrict__ bbw2,
                     const float* __restrict__ latw1, const float* __restrict__ latw2,
                     float* __restrict__ radbb, float* __restrict__ radlat){
  int e = blockIdx.x*256 + threadIdx.x;
  float f[32];
  load32(f, ef + (size_t)e*32);
  float h[64];
  // ---- bb branch: 32->64(silu)->7 ----
  #pragma unroll
  for(int o=0;o<64;o++) h[o]=0.f;
  #pragma unroll
  for(int c=0;c<32;c++){
    const float* w = bbw1 + c*64;
    #pragma unroll
    for(int o=0;o<64;o++) h[o] += f[c]*w[o];
  }
  float ab[7];
  #pragma unroll
  for(int t=0;t<7;t++) ab[t]=0.f;
  #pragma unroll
  for(int o=0;o<64;o++){
    float v = siluf(h[o]);
    const float* w2 = bbw2 + o*7;
    #pragma unroll
    for(int t=0;t<7;t++) ab[t] += v*w2[t];
  }
  {
    float4* rb4 = (float4*)(radbb + (size_t)e*8);
    rb4[0] = make_float4(ab[0],ab[1],ab[2],ab[3]);
    rb4[1] = make_float4(ab[4],ab[5],ab[6],0.f);
  }
  // ---- lat branch: 32->64(silu)->32 ----
  #pragma unroll
  for(int o=0;o<64;o++) h[o]=0.f;
  #pragma unroll
  for(int c=0;c<32;c++){
    const float* w = latw1 + c*64;
    #pragma unroll
    for(int o=0;o<64;o++) h[o] += f[c]*w[o];
  }
  float al[32];
  #pragma unroll
  for(int t=0;t<32;t++) al[t]=0.f;
  #pragma unroll
  for(int o=0;o<64;o++){
    float v = siluf(h[o]);
    const float* w2 = latw2 + o*32;
    #pragma unroll
    for(int t=0;t<32;t++) al[t] += v*w2[t];
  }
  float4* rl4 = (float4*)(radlat + (size_t)e*32);
  #pragma unroll
  for(int q=0;q<8;q++) rl4[q] = make_float4(al[q*4],al[q*4+1],al[q*4+2],al[q*4+3]);
}

// ---------------- K4: init gather + out-proj + fused norm (wave/node) ----------------
__global__ __launch_bounds__(256) void k_init(const int* __restrict__ nbr,
                       const float* __restrict__ radbb, const float* __restrict__ radlat,
                       const float* __restrict__ bbf, const float* __restrict__ latn,
                       const float* __restrict__ bboutw, const float* __restrict__ latoutw,
                       const float* __restrict__ g0, const float* __restrict__ b0,
                       const float* __restrict__ g1,
                       float* __restrict__ x, float* __restrict__ xl){
  __shared__ float msgbb[4][32], msglat[4][128], xout[4][128];
  int g = threadIdx.x>>6, t = threadIdx.x&63;
  int n = blockIdx.x*4 + g;
  int t31 = t&31, t7 = t%7;
  float accL0=0.f, accL1=0.f, accB=0.f;
  for(int kk=0; kk<KNB; kk++){
    int e = n*KNB+kk;
    int j = nbr[e];
    float rl = radlat[(size_t)e*32 + t31];
    accL0 += latn[j*128+t]    * rl;
    accL1 += latn[j*128+64+t] * rl;
    if(t<28) accB += bbf[j*28+t]*radbb[(size_t)e*8 + t7];
  }
  msglat[g][t]=accL0*(1.0f/KNB); msglat[g][64+t]=accL1*(1.0f/KNB);
  if(t<28) msgbb[g][t]=accB*(1.0f/KNB);
  for(int half=0; half<2; half++){
    int e = half*64+t;
    int rrow = e>>5, c = e&31;
    float v=0.f;
    if(c<16){ for(int q=0;q<7;q++)  v += msgbb[g][rrow*7+q]*bboutw[q*16+c]; }
    else    { for(int q=0;q<32;q++) v += msglat[g][rrow*32+q]*latoutw[q*16+(c-16)]; }
    xout[g][e]=v;
    x[n*128+e]=v;
  }
  if(t<32){
    float x0=xout[g][t];
    float s=x0, s2=x0*x0;
    for(int off=16; off>0; off>>=1){ s+=__shfl_xor(s,off,32); s2+=__shfl_xor(s2,off,32); }
    float mu=s*(1.0f/32.0f), var=s2*(1.0f/32.0f)-mu*mu;
    float y0=(x0-mu)*rsqrtf(var+1e-6f)*g0[t]+b0[t];
    float v1=xout[g][32+t], v2=xout[g][64+t], v3=xout[g][96+t];
    float ss=v1*v1+v2*v2+v3*v3;
    for(int off=16; off>0; off>>=1) ss+=__shfl_xor(ss,off,32);
    float sc=rsqrtf(ss*(1.0f/96.0f)+1e-6f);
    float gg=g1[t];
    xl[n*128+t]=y0; xl[n*128+32+t]=v1*sc*gg; xl[n*128+64+t]=v2*sc*gg; xl[n*128+96+t]=v3*sc*gg;
  }
}

// ---------------- K5: attention logits, lane-per-edge, all-register -> (E,8) ----------------
__global__ __launch_bounds__(256,4) void k_logits(const int* __restrict__ nbr, const float* __restrict__ xl,
                         const float* __restrict__ ef, const float* __restrict__ w1,
                         const float* __restrict__ w2, float* __restrict__ logits){
  int e = blockIdx.x*256 + threadIdx.x;
  int n = e/KNB;
  int j = nbr[e];
  float h[32];
  #pragma unroll
  for(int o=0;o<32;o++) h[o]=0.f;
  float f[32];
  load32(f, xl + (size_t)j*128);
  #pragma unroll
  for(int c=0;c<32;c++){
    const float* w = w1 + c*32;
    #pragma unroll
    for(int o=0;o<32;o++) h[o] += f[c]*w[o];
  }
  load32(f, xl + (size_t)n*128);
  #pragma unroll
  for(int c=0;c<32;c++){
    const float* w = w1 + (32+c)*32;
    #pragma unroll
    for(int o=0;o<32;o++) h[o] += f[c]*w[o];
  }
  load32(f, ef + (size_t)e*32);
  #pragma unroll
  for(int c=0;c<32;c++){
    const float* w = w1 + (64+c)*32;
    #pragma unroll
    for(int o=0;o<32;o++) h[o] += f[c]*w[o];
  }
  float acc[8];
  #pragma unroll
  for(int t=0;t<8;t++) acc[t]=0.f;
  #pragma unroll
  for(int o=0;o<32;o++){
    float v = siluf(h[o]);
    const float* w = w2 + o*8;
    #pragma unroll
    for(int t=0;t<8;t++) acc[t] += v*w[t];
  }
  float4* lg4 = (float4*)(logits + (size_t)e*8);
  lg4[0] = make_float4(acc[0],acc[1],acc[2],acc[3]);
  lg4[1] = make_float4(acc[4],acc[5],acc[6],acc[7]);
}

// ---------------- K7: softmax + aggregate (float4 gather) + o_w + FFN + fused norm ----------------
__global__ __launch_bounds__(256) void k_update(const int* __restrict__ nbr, const float* __restrict__ xl,
                         const float* __restrict__ logits, float* __restrict__ x,
                         float* __restrict__ xlout,
                         const float* __restrict__ vw, const float* __restrict__ ow,
                         const float* __restrict__ fw1, const float* __restrict__ fw2,
                         const float* __restrict__ fwg, const float* __restrict__ fv1,
                         const float* __restrict__ g0, const float* __restrict__ b0,
                         const float* __restrict__ g1){
  __shared__ float S_lg[4][240], S_m[4][8], S_inv[4][8];
  __shared__ float S_S[4][1024], S_agg[4][512], S_x[4][128];
  __shared__ float S_h[4][64], S_g[4][32], S_d0[4][32];
  int g = threadIdx.x>>6, t = threadIdx.x&63;
  int n = blockIdx.x*4 + g;
  for(int r=t; r<240; r+=64) S_lg[g][r] = logits[(size_t)n*240+r];
  if(t<8){
    float m=-1e30f;
    for(int kk=0;kk<KNB;kk++) m=fmaxf(m, S_lg[g][kk*8+t]);
    float s=0.f;
    for(int kk=0;kk<KNB;kk++) s += __expf(S_lg[g][kk*8+t]-m);
    S_m[g][t]=m; S_inv[g][t]=1.0f/s;
  }
  for(int r=t; r<240; r+=64){ int h=r&7; S_lg[g][r]=__expf(S_lg[g][r]-S_m[g][h])*S_inv[g][h]; }
  int hd = t>>3, i8 = t&7;
  const float4* xl4 = (const float4*)xl;
  float acc[16];
  for(int m=0;m<16;m++) acc[m]=0.f;
  for(int kk=0;kk<KNB;kk++){
    int j=nbr[n*KNB+kk];
    float a = S_lg[g][kk*8+hd];
    float4 b0v = xl4[j*32 + i8*4 + 0];
    float4 b1v = xl4[j*32 + i8*4 + 1];
    float4 b2v = xl4[j*32 + i8*4 + 2];
    float4 b3v = xl4[j*32 + i8*4 + 3];
    acc[0]+=a*b0v.x; acc[1]+=a*b0v.y; acc[2]+=a*b0v.z; acc[3]+=a*b0v.w;
    acc[4]+=a*b1v.x; acc[5]+=a*b1v.y; acc[6]+=a*b1v.z; acc[7]+=a*b1v.w;
    acc[8]+=a*b2v.x; acc[9]+=a*b2v.y; acc[10]+=a*b2v.z; acc[11]+=a*b2v.w;
    acc[12]+=a*b3v.x; acc[13]+=a*b3v.y; acc[14]+=a*b3v.z; acc[15]+=a*b3v.w;
  }
  for(int m=0;m<16;m++) S_S[g][hd*128 + i8*16 + m] = acc[m];
  for(int half=0; half<2; half++){
    int hv = half*64+t;
    int hh = hv>>4;
    float a0=0.f,a1=0.f,a2=0.f,a3=0.f;
    for(int c=0;c<32;c++){
      float w = vw[c*128+hv];
      a0 += S_S[g][hh*128 + c]*w;
      a1 += S_S[g][hh*128 + 32+c]*w;
      a2 += S_S[g][hh*128 + 64+c]*w;
      a3 += S_S[g][hh*128 + 96+c]*w;
    }
    S_agg[g][hv]=a0; S_agg[g][128+hv]=a1; S_agg[g][256+hv]=a2; S_agg[g][384+hv]=a3;
  }
  for(int half=0; half<2; half++){
    int e = half*64+t;
    int rrow = e>>5, c = e&31;
    float v = x[n*128+e];
    for(int hv=0;hv<128;hv++) v += S_agg[g][rrow*128+hv]*ow[hv*32+c];
    S_x[g][e]=v;
  }
  {
    float hs=0.f;
    for(int c=0;c<32;c++) hs += S_x[g][c]*fw1[c*64+t];
    S_h[g][t]=siluf(hs);
  }
  if(t<32){
    float gs=0.f, d0=0.f;
    for(int c=0;c<64;c++){ float hv=S_h[g][c]; gs += hv*fwg[c*32+t]; d0 += hv*fw2[c*32+t]; }
    S_g[g][t]=1.0f/(1.0f+__expf(-gs));
    S_d0[g][t]=d0;
  }
  for(int half=0; half<2; half++){
    int e = half*64+t;
    int rrow = e>>5, c = e&31;
    float xv = S_x[g][e], outv;
    if(rrow==0){ outv = xv + S_d0[g][c]; }
    else {
      float dv=0.f;
      for(int cc=0;cc<32;cc++) dv += S_x[g][rrow*32+cc]*fv1[cc*32+c];
      outv = xv + dv*S_g[g][c];
    }
    S_x[g][e]=outv;
    x[n*128+e]=outv;
  }
  if(t<32){
    float x0=S_x[g][t];
    float s=x0, s2=x0*x0;
    for(int off=16; off>0; off>>=1){ s+=__shfl_xor(s,off,32); s2+=__shfl_xor(s2,off,32); }
    float mu=s*(1.0f/32.0f), var=s2*(1.0f/32.0f)-mu*mu;
    float y0=(x0-mu)*rsqrtf(var+1e-6f)*g0[t]+b0[t];
    float v1=S_x[g][32+t], v2=S_x[g][64+t], v3=S_x[g][96+t];
    float ss=v1*v1+v2*v2+v3*v3;
    for(int off=16; off>0; off>>=1) ss+=__shfl_xor(ss,off,32);
    float sc=rsqrtf(ss*(1.0f/96.0f)+1e-6f);
    float gg=g1[t];
    xlout[n*128+t]=y0; xlout[n*128+32+t]=v1*sc*gg;
    xlout[n*128+64+t]=v2*sc*gg; xlout[n*128+96+t]=v3*sc*gg;
  }
}

// ---------------- K8: edge update, lane-per-edge, all-register ----------------
// feat rows: 0..31 ef, 32..63 x[j], 64..95 x[n]; ew1 (96x64), ew2 (64x32)
__global__ __launch_bounds__(256,4) void k_efup(const int* __restrict__ nbr, const float* __restrict__ x,
                       const float* __restrict__ ew1, const float* __restrict__ ew2,
                       float* __restrict__ ef){
  int e = blockIdx.x*256 + threadIdx.x;
  int n = e/KNB;
  int j = nbr[e];
  float h[64];
  #pragma unroll
  for(int o=0;o<64;o++) h[o]=0.f;
  float f[32];
  load32(f, ef + (size_t)e*32);
  #pragma unroll
  for(int c=0;c<32;c++){
    const float* w = ew1 + c*64;
    #pragma unroll
    for(int o=0;o<64;o++) h[o] += f[c]*w[o];
  }
  load32(f, x + (size_t)j*128);
  #pragma unroll
  for(int c=0;c<32;c++){
    const float* w = ew1 + (32+c)*64;
    #pragma unroll
    for(int o=0;o<64;o++) h[o] += f[c]*w[o];
  }
  load32(f, x + (size_t)n*128);
  #pragma unroll
  for(int c=0;c<32;c++){
    const float* w = ew1 + (64+c)*64;
    #pragma unroll
    for(int o=0;o<64;o++) h[o] += f[c]*w[o];
  }
  float acc[32];
  #pragma unroll
  for(int t=0;t<32;t++) acc[t]=0.f;
  #pragma unroll
  for(int o=0;o<64;o++){
    float v = siluf(h[o]);
    const float* w = ew2 + o*32;
    #pragma unroll
    for(int t=0;t<32;t++) acc[t] += v*w[t];
  }
  // reload ef (L1-hot) and write residual
  load32(f, ef + (size_t)e*32);
  float4* e4 = (float4*)(ef + (size_t)e*32);
  #pragma unroll
  for(int q=0;q<8;q++){
    e4[q] = make_float4(f[q*4+0]+acc[q*4+0], f[q*4+1]+acc[q*4+1],
                        f[q*4+2]+acc[q*4+2], f[q*4+3]+acc[q*4+3]);
  }
}

// ---------------- K9a: out radial MLP, lane-per-edge, all-register -> orad (E,32) ----------------
__global__ __launch_bounds__(256,4) void k_orad(const float* __restrict__ ef,
                      const float* __restrict__ orw1, const float* __restrict__ orw2,
                      float* __restrict__ orad){
  int e = blockIdx.x*256 + threadIdx.x;
  float f[32];
  load32(f, ef + (size_t)e*32);
  float h[64];
  #pragma unroll
  for(int o=0;o<64;o++) h[o]=0.f;
  #pragma unroll
  for(int c=0;c<32;c++){
    const float* w = orw1 + c*64;
    #pragma unroll
    for(int o=0;o<64;o++) h[o] += f[c]*w[o];
  }
  float acc[32];
  #pragma unroll
  for(int t=0;t<32;t++) acc[t]=0.f;
  #pragma unroll
  for(int o=0;o<64;o++){
    float v = siluf(h[o]);
    const float* w = orw2 + o*32;
    #pragma unroll
    for(int t=0;t<32;t++) acc[t] += v*w[t];
  }
  float4* r4 = (float4*)(orad + (size_t)e*32);
  #pragma unroll
  for(int q=0;q<8;q++) r4[q] = make_float4(acc[q*4],acc[q*4+1],acc[q*4+2],acc[q*4+3]);
}

// ---------------- K9: out gather + projection + fused seq head ----------------
__global__ __launch_bounds__(256) void k_out(const int* __restrict__ nbr, const float* __restrict__ orad,
                      const float* __restrict__ x,
                      const float* __restrict__ outw,
                      const float* __restrict__ sw1, const float* __restrict__ sb1,
                      const float* __restrict__ sw2, const float* __restrict__ sb2,
                      const float* __restrict__ sw3, const float* __restrict__ sb3,
                      float* __restrict__ out, float* __restrict__ outseq){
  __shared__ float msg[4][128];
  __shared__ float h1[4][64], h2[4][32], lgs[4][20];
  int g = threadIdx.x>>6, t = threadIdx.x&63;
  int n = blockIdx.x*4 + g;
  int t31 = t&31;
  float acc0=0.f, acc1=0.f;
  for(int kk=0;kk<KNB;kk++){
    int e=n*KNB+kk;
    int j=nbr[e];
    float rl = orad[(size_t)e*32 + t31];
    acc0 += x[j*128+t]*rl;
    acc1 += x[j*128+64+t]*rl;
  }
  msg[g][t]=acc0*(1.0f/KNB); msg[g][64+t]=acc1*(1.0f/KNB);
  for(int o=t;o<91;o+=64){
    for(int rrow=1;rrow<4;rrow++){
      float s=0.f;
      for(int c=0;c<32;c++) s += msg[g][rrow*32+c]*outw[c*91+o];
      out[(size_t)n*273 + o*3 + (rrow-1)] = s;
    }
  }
  {
    float s=0.f;
    for(int c=0;c<32;c++) s += x[n*128+c]*sw1[c*64+t];
    h1[g][t]=fmaxf(s+sb1[t],0.f);
  }
  if(t<32){
    float s=0.f;
    for(int c=0;c<64;c++) s += h1[g][c]*sw2[c*32+t];
    h2[g][t]=fmaxf(s+sb2[t],0.f);
  }
  if(t<20){
    float s=0.f;
    for(int c=0;c<32;c++) s += h2[g][c]*sw3[c*20+t];
    lgs[g][t]=s+sb3[t];
  }
  if(t<20){
    float m=-1e30f;
    for(int c=0;c<20;c++) m=fmaxf(m,lgs[g][c]);
    float se=0.f;
    for(int c=0;c<20;c++) se += __expf(lgs[g][c]-m);
    outseq[(size_t)n*20+t]=lgs[g][t]-m-logf(se);
  }
}

extern "C" void kernel_launch(void* const* d_in, const int* in_sizes, int n_in,
                              void* d_out, int out_size, void* d_ws, size_t ws_size,
                              hipStream_t stream) {
  const float* bb      = (const float*)d_in[0];
  const float* latent  = (const float*)d_in[1];
  const float* ln_g0   = (const float*)d_in[2];
  const float* ln_b0   = (const float*)d_in[3];
  const float* ln_g1   = (const float*)d_in[4];
  const float* bbw1    = (const float*)d_in[5];
  const float* bbw2    = (const float*)d_in[6];
  const float* bboutw  = (const float*)d_in[7];
  const float* latw1   = (const float*)d_in[8];
  const float* latw2   = (const float*)d_in[9];
  const float* latoutw = (const float*)d_in[10];
  const float* tg0     = (const float*)d_in[11];
  const float* tb0     = (const float*)d_in[12];
  const float* tg1     = (const float*)d_in[13];
  const float* aw1     = (const float*)d_in[14];
  const float* aw2     = (const float*)d_in[15];
  const float* vw      = (const float*)d_in[16];
  const float* ow      = (const float*)d_in[17];
  const float* fw1     = (const float*)d_in[18];
  const float* fw2     = (const float*)d_in[19];
  const float* fwg     = (const float*)d_in[20];
  const float* fv1     = (const float*)d_in[21];
  const float* ew1     = (const float*)d_in[22];
  const float* ew2     = (const float*)d_in[23];
  const float* orw1    = (const float*)d_in[24];
  const float* orw2    = (const float*)d_in[25];
  const float* outw    = (const float*)d_in[26];
  const float* sw1     = (const float*)d_in[27];
  const float* sb1     = (const float*)d_in[28];
  const float* sw2     = (const float*)d_in[29];
  const float* sb2     = (const float*)d_in[30];
  const float* sw3     = (const float*)d_in[31];
  const float* sb3     = (const float*)d_in[32];
  float* outp = (float*)d_out;

  // workspace layout (radbb overlays logits; orad overlays radlat)
  int*    nbr    = (int*)d_ws;
  float*  ef     = (float*)((char*)d_ws + 1024*1024);
  float*  xbuf   = ef   + (size_t)NEDGE*32;
  float*  xlA    = xbuf + (size_t)NRES*128;
  float*  xlB    = xlA  + (size_t)NRES*128;
  float*  bbf    = xlB  + (size_t)NRES*128;
  float*  logits = bbf  + (size_t)NRES*28;
  float4* ca     = (float4*)(logits + (size_t)NEDGE*8);
  float*  edgescratch = (float*)(ca + NRES);     // NEDGE*32 floats
  float*  radbb  = logits;                       // NEDGE*8, dead before first k_logits
  float*  radlat = edgescratch;                  // NEDGE*32, dead after k_init
  float*  orad   = edgescratch;                  // reused at the end

  k_bbfeat  <<<NRES/256, 256, 0, stream>>>(bb, bbf, ca);
  k_knn     <<<NRES/8,   512, 0, stream>>>(ca, nbr);
  k_edgefeat<<<NEDGE/256, 256, 0, stream>>>(ca, nbr, ef);
  k_norm    <<<NRES*32/256, 256, 0, stream>>>(latent, xlA, ln_g0, ln_b0, ln_g1);
  k_rad     <<<NEDGE/256, 256, 0, stream>>>(ef, bbw1, bbw2, latw1, latw2, radbb, radlat);
  k_init    <<<NRES/4, 256, 0, stream>>>(nbr, radbb, radlat, bbf, xlA,
                                         bboutw, latoutw,
                                         tg0, tb0, tg1,
                                         xbuf, xlB);
  for(int l=0;l<4;l++){
    const float* xl_in  = (l&1) ? xlA : xlB;
    float*       xl_out = (l&1) ? xlB : xlA;
    int ln = (l+1<4) ? (l+1) : 3;
    k_logits <<<NEDGE/256, 256, 0, stream>>>(nbr, xl_in, ef, aw1+l*96*32, aw2+l*32*8, logits);
    k_update <<<NRES/4, 256, 0, stream>>>(nbr, xl_in, logits, xbuf, xl_out,
                                          vw+l*32*128, ow+l*128*32,
                                          fw1+l*32*64, fw2+l*64*32,
                                          fwg+l*64*32, fv1+l*32*32,
                                          tg0+ln*32, tb0+ln*32, tg1+ln*32);
    k_efup   <<<NEDGE/256, 256, 0, stream>>>(nbr, xbuf, ew1+l*96*64, ew2+l*64*32, ef);
  }
  k_orad<<<NEDGE/256, 256, 0, stream>>>(ef, orw1, orw2, orad);
  k_out <<<NRES/4, 256, 0, stream>>>(nbr, orad, xbuf, outw,
                                     sw1, sb1, sw2, sb2, sw3, sb3,
                                     outp, outp + (size_t)NRES*273);
}

// Round 14
// 1296.204 us; speedup vs baseline: 1.2182x; 1.2182x over previous
//
#include <hip/hip_runtime.h>
#include <math.h>

#define NRES 8192
#define NPER 2048
#define KNB  30
#define NEDGE (NRES*KNB)

__device__ __forceinline__ float siluf(float x){ return x / (1.0f + __expf(-x)); }

// ---------------- K0: backbone features + ca pack ----------------
__global__ void k_bbfeat(const float* __restrict__ bb, float* __restrict__ bbf,
                         float4* __restrict__ ca){
  int n = blockIdx.x*256 + threadIdx.x;
  if(n >= NRES) return;
  const float* r = bb + n*12;
  float cax=r[3], cay=r[4], caz=r[5];
  ca[n] = make_float4(cax,cay,caz, cax*cax+cay*cay+caz*caz);
  float vx[7],vy[7],vz[7];
  for(int a=0;a<4;a++){ vx[a]=r[a*3]-cax; vy[a]=r[a*3+1]-cay; vz[a]=r[a*3+2]-caz; }
  if(n<NRES-1){
    float dx=bb[(n+1)*12+3]-cax, dy=bb[(n+1)*12+4]-cay, dz=bb[(n+1)*12+5]-caz;
    float s=rsqrtf(dx*dx+dy*dy+dz*dz+1e-8f);
    vx[4]=dx*s; vy[4]=dy*s; vz[4]=dz*s;
  } else { vx[4]=0.f; vy[4]=0.f; vz[4]=0.f; }
  if(n>0){
    float dx=bb[(n-1)*12+3]-cax, dy=bb[(n-1)*12+4]-cay, dz=bb[(n-1)*12+5]-caz;
    float s=rsqrtf(dx*dx+dy*dy+dz*dz+1e-8f);
    vx[5]=dx*s; vy[5]=dy*s; vz[5]=dz*s;
  } else { vx[5]=0.f; vy[5]=0.f; vz[5]=0.f; }
  {
    float bx=cax-r[0], by=cay-r[1], bz=caz-r[2];
    float cx=r[6]-cax, cy=r[7]-cay, cz=r[8]-caz;
    float axx=by*cz-bz*cy, ayy=bz*cx-bx*cz, azz=bx*cy-by*cx;
    vx[6]=-0.58273431f*axx+0.56802827f*bx-0.54067466f*cx;
    vy[6]=-0.58273431f*ayy+0.56802827f*by-0.54067466f*cy;
    vz[6]=-0.58273431f*azz+0.56802827f*bz-0.54067466f*cz;
  }
  float cD[3], sD[3];
  for(int t=0;t<3;t++){
    cD[t]=1.0f; sD[t]=0.0f;
    int f=3*n+t-1;
    if(f>=0 && f<3*NRES-3){
      float X[4][3];
      for(int q=0;q<4;q++){
        int m=f+q, rr=m/3, aa=m-rr*3;
        X[q][0]=bb[rr*12+aa*3]; X[q][1]=bb[rr*12+aa*3+1]; X[q][2]=bb[rr*12+aa*3+2];
      }
      float u2x=X[1][0]-X[0][0], u2y=X[1][1]-X[0][1], u2z=X[1][2]-X[0][2];
      float u1x=X[2][0]-X[1][0], u1y=X[2][1]-X[1][1], u1z=X[2][2]-X[1][2];
      float u0x=X[3][0]-X[2][0], u0y=X[3][1]-X[2][1], u0z=X[3][2]-X[2][2];
      float s2=rsqrtf(u2x*u2x+u2y*u2y+u2z*u2z+1e-8f); u2x*=s2; u2y*=s2; u2z*=s2;
      float s1=rsqrtf(u1x*u1x+u1y*u1y+u1z*u1z+1e-8f); u1x*=s1; u1y*=s1; u1z*=s1;
      float s0=rsqrtf(u0x*u0x+u0y*u0y+u0z*u0z+1e-8f); u0x*=s0; u0y*=s0; u0z*=s0;
      float n2x=u2y*u1z-u2z*u1y, n2y=u2z*u1x-u2x*u1z, n2z=u2x*u1y-u2y*u1x;
      float nn2=rsqrtf(n2x*n2x+n2y*n2y+n2z*n2z+1e-8f); n2x*=nn2; n2y*=nn2; n2z*=nn2;
      float n1x=u1y*u0z-u1z*u0y, n1y=u1z*u0x-u1x*u0z, n1z=u1x*u0y-u1y*u0x;
      float nn1=rsqrtf(n1x*n1x+n1y*n1y+n1z*n1z+1e-8f); n1x*=nn1; n1y*=nn1; n1z*=nn1;
      float dotn = n2x*n1x+n2y*n1y+n2z*n1z;
      float cosD = fminf(fmaxf(dotn, -1.0f+1e-6f), 1.0f-1e-6f);
      float sg = u2x*n1x+u2y*n1y+u2z*n1z;
      if(sg==0.0f){ cD[t]=1.0f; sD[t]=0.0f; }
      else {
        float sgn = (sg>0.0f)?1.0f:-1.0f;
        cD[t]=cosD;
        sD[t]=sgn*sqrtf(fmaxf(1.0f-cosD*cosD,0.0f));
      }
    }
  }
  float* o = bbf + n*28;
  o[0]=cD[0]; o[1]=cD[1]; o[2]=cD[2]; o[3]=sD[0]; o[4]=sD[1]; o[5]=sD[2]; o[6]=0.f;
  for(int c=0;c<7;c++){ o[7+c]=vx[c]; o[14+c]=vy[c]; o[21+c]=vz[c]; }
}

// ---------------- K1: kNN — wave-per-query, LDS-staged coords (validated 109us) ----------------
__global__ __launch_bounds__(256) void k_knn(const float4* __restrict__ ca, int* __restrict__ nbr){
  __shared__ float sx[NPER], sy[NPER], sz[NPER], sq[NPER];
  int wave = threadIdx.x>>6;
  int lane = threadIdx.x&63;
  int i = blockIdx.x*4 + wave;
  int batch = i / NPER;
  int base = batch*NPER;
  for(int t=threadIdx.x; t<NPER; t+=256){
    float4 c = ca[base+t];
    sx[t]=c.x; sy[t]=c.y; sz[t]=c.z; sq[t]=c.w;
  }
  __syncthreads();
  int il = i - base;
  float xi=sx[il], yi=sy[il], zi=sz[il], si=sq[il];
  float vals[32];
  float lmin = 1e30f; int larg = 0;
  #pragma unroll
  for(int t=0;t<32;t++){
    int j = t*64 + lane;
    float d2 = si + sq[j] - 2.0f*(xi*sx[j]+yi*sy[j]+zi*sz[j]);
    if(j==il) d2 = 1e30f;
    vals[t]=d2;
    if(d2 < lmin){ lmin=d2; larg=t; }
  }
  for(int it=0; it<KNB; it++){
    float v = lmin; int jg = larg*64 + lane;
    #pragma unroll
    for(int off=32; off>0; off>>=1){
      float vo = __shfl_xor(v, off, 64);
      int   jo = __shfl_xor(jg, off, 64);
      if(vo < v || (vo==v && jo<jg)){ v=vo; jg=jo; }
    }
    if(lane==0) nbr[i*KNB+it] = base + jg;
    if((jg&63)==lane){
      int targ = jg>>6;
      lmin = 1e30f; larg = 0;
      #pragma unroll
      for(int t=0;t<32;t++){
        if(t==targ) vals[t]=1e30f;
        if(vals[t]<lmin){ lmin=vals[t]; larg=t; }
      }
    }
  }
}

// ---------------- K2: edge features ef (N,k,32) = [rbf16, cos8, sin8] ----------------
__global__ void k_edgefeat(const float4* __restrict__ ca, const int* __restrict__ nbr,
                           float* __restrict__ ef){
  int e = blockIdx.x*256 + threadIdx.x;
  if(e >= NEDGE) return;
  int n = e/KNB;
  int j = nbr[e];
  float4 cn = ca[n], cj = ca[j];
  float dx=cn.x-cj.x, dy=cn.y-cj.y, dz=cn.z-cj.z;
  float dist = sqrtf(dx*dx+dy*dy+dz*dz + 1e-12f);
  float f[32];
  #pragma unroll
  for(int m=0;m<16;m++){
    float mu = (20.0f/15.0f)*(float)m;
    float t = (dist-mu)*(1.0f/1.25f);
    f[m] = __expf(-t*t);
  }
  float didx = (float)(j - n);
  #pragma unroll
  for(int m=0;m<8;m++){
    float freq = __expf(-1.1512925465f*(float)m);  // 10000^(-m/8)
    float ang = didx*freq;
    f[16+m]=cosf(ang); f[24+m]=sinf(ang);
  }
  float4* o4 = (float4*)(ef + (size_t)e*32);
  #pragma unroll
  for(int q=0;q<8;q++) o4[q] = make_float4(f[q*4],f[q*4+1],f[q*4+2],f[q*4+3]);
}

// ---------------- K3: norm_so3 (latent only) ----------------
__global__ void k_norm(const float* __restrict__ in, float* __restrict__ out,
                       const float* __restrict__ g0, const float* __restrict__ b0,
                       const float* __restrict__ g1){
  int tid = blockIdx.x*256 + threadIdx.x;
  int n = tid >> 5, lane = tid & 31;
  if(n >= NRES) return;
  const float* xn = in + n*128;
  float x0 = xn[lane];
  float s = x0, s2 = x0*x0;
  for(int off=16; off>0; off>>=1){ s += __shfl_xor(s, off, 32); s2 += __shfl_xor(s2, off, 32); }
  float mu = s*(1.0f/32.0f);
  float var = s2*(1.0f/32.0f) - mu*mu;
  float y0 = (x0-mu)*rsqrtf(var+1e-6f)*g0[lane] + b0[lane];
  float v1 = xn[32+lane], v2 = xn[64+lane], v3 = xn[96+lane];
  float ss = v1*v1+v2*v2+v3*v3;
  for(int off=16; off>0; off>>=1){ ss += __shfl_xor(ss, off, 32); }
  float sc = rsqrtf(ss*(1.0f/96.0f) + 1e-6f);
  float g = g1[lane];
  out[n*128+lane]     = y0;
  out[n*128+32+lane]  = v1*sc*g;
  out[n*128+64+lane]  = v2*sc*g;
  out[n*128+96+lane]  = v3*sc*g;
}

// helper: load 32 floats into a register array (callers index with constants only)
__device__ __forceinline__ void load32(float* __restrict__ f, const float* __restrict__ src){
  const float4* s4 = (const float4*)src;
  #pragma unroll
  for(int q=0;q<8;q++){
    float4 v = s4[q];
    f[q*4+0]=v.x; f[q*4+1]=v.y; f[q*4+2]=v.z; f[q*4+3]=v.w;
  }
}

// ---------------- K4a: init radial MLPs, lane-per-edge, all-register ----------------
__global__ __launch_bounds__(256,4) void k_rad(const float* __restrict__ ef,
                     const float* __restrict__ bbw1, const float* __restrict__ bbw2,
                     const float* __restrict__ latw1, const float* __restrict__ latw2,
                     float* __restrict__ radbb, float* __restrict__ radlat){
  int e = blockIdx.x*256 + threadIdx.x;
  float f[32];
  load32(f, ef + (size_t)e*32);
  float h[64];
  // ---- bb branch: 32->64(silu)->7 ----
  #pragma unroll
  for(int o=0;o<64;o++) h[o]=0.f;
  #pragma unroll
  for(int c=0;c<32;c++){
    const float* w = bbw1 + c*64;
    #pragma unroll
    for(int o=0;o<64;o++) h[o] += f[c]*w[o];
  }
  float ab[7];
  #pragma unroll
  for(int t=0;t<7;t++) ab[t]=0.f;
  #pragma unroll
  for(int o=0;o<64;o++){
    float v = siluf(h[o]);
    const float* w2 = bbw2 + o*7;
    #pragma unroll
    for(int t=0;t<7;t++) ab[t] += v*w2[t];
  }
  {
    float4* rb4 = (float4*)(radbb + (size_t)e*8);
    rb4[0] = make_float4(ab[0],ab[1],ab[2],ab[3]);
    rb4[1] = make_float4(ab[4],ab[5],ab[6],0.f);
  }
  // ---- lat branch: 32->64(silu)->32 ----
  #pragma unroll
  for(int o=0;o<64;o++) h[o]=0.f;
  #pragma unroll
  for(int c=0;c<32;c++){
    const float* w = latw1 + c*64;
    #pragma unroll
    for(int o=0;o<64;o++) h[o] += f[c]*w[o];
  }
  float al[32];
  #pragma unroll
  for(int t=0;t<32;t++) al[t]=0.f;
  #pragma unroll
  for(int o=0;o<64;o++){
    float v = siluf(h[o]);
    const float* w2 = latw2 + o*32;
    #pragma unroll
    for(int t=0;t<32;t++) al[t] += v*w2[t];
  }
  float4* rl4 = (float4*)(radlat + (size_t)e*32);
  #pragma unroll
  for(int q=0;q<8;q++) rl4[q] = make_float4(al[q*4],al[q*4+1],al[q*4+2],al[q*4+3]);
}

// ---------------- K4: init gather + out-proj + fused norm (wave/node) ----------------
__global__ __launch_bounds__(256) void k_init(const int* __restrict__ nbr,
                       const float* __restrict__ radbb, const float* __restrict__ radlat,
                       const float* __restrict__ bbf, const float* __restrict__ latn,
                       const float* __restrict__ bboutw, const float* __restrict__ latoutw,
                       const float* __restrict__ g0, const float* __restrict__ b0,
                       const float* __restrict__ g1,
                       float* __restrict__ x, float* __restrict__ xl){
  __shared__ float msgbb[4][32], msglat[4][128], xout[4][128];
  int g = threadIdx.x>>6, t = threadIdx.x&63;
  int n = blockIdx.x*4 + g;
  int t31 = t&31, t7 = t%7;
  float accL0=0.f, accL1=0.f, accB=0.f;
  for(int kk=0; kk<KNB; kk++){
    int e = n*KNB+kk;
    int j = nbr[e];
    float rl = radlat[(size_t)e*32 + t31];
    accL0 += latn[j*128+t]    * rl;
    accL1 += latn[j*128+64+t] * rl;
    if(t<28) accB += bbf[j*28+t]*radbb[(size_t)e*8 + t7];
  }
  msglat[g][t]=accL0*(1.0f/KNB); msglat[g][64+t]=accL1*(1.0f/KNB);
  if(t<28) msgbb[g][t]=accB*(1.0f/KNB);
  for(int half=0; half<2; half++){
    int e = half*64+t;
    int rrow = e>>5, c = e&31;
    float v=0.f;
    if(c<16){ for(int q=0;q<7;q++)  v += msgbb[g][rrow*7+q]*bboutw[q*16+c]; }
    else    { for(int q=0;q<32;q++) v += msglat[g][rrow*32+q]*latoutw[q*16+(c-16)]; }
    xout[g][e]=v;
    x[n*128+e]=v;
  }
  if(t<32){
    float x0=xout[g][t];
    float s=x0, s2=x0*x0;
    for(int off=16; off>0; off>>=1){ s+=__shfl_xor(s,off,32); s2+=__shfl_xor(s2,off,32); }
    float mu=s*(1.0f/32.0f), var=s2*(1.0f/32.0f)-mu*mu;
    float y0=(x0-mu)*rsqrtf(var+1e-6f)*g0[t]+b0[t];
    float v1=xout[g][32+t], v2=xout[g][64+t], v3=xout[g][96+t];
    float ss=v1*v1+v2*v2+v3*v3;
    for(int off=16; off>0; off>>=1) ss+=__shfl_xor(ss,off,32);
    float sc=rsqrtf(ss*(1.0f/96.0f)+1e-6f);
    float gg=g1[t];
    xl[n*128+t]=y0; xl[n*128+32+t]=v1*sc*gg; xl[n*128+64+t]=v2*sc*gg; xl[n*128+96+t]=v3*sc*gg;
  }
}

// ---------------- K5: attention logits (standalone, layer 0 only) ----------------
__global__ __launch_bounds__(256,4) void k_logits(const int* __restrict__ nbr, const float* __restrict__ xl,
                         const float* __restrict__ ef, const float* __restrict__ w1,
                         const float* __restrict__ w2, float* __restrict__ logits){
  int e = blockIdx.x*256 + threadIdx.x;
  int n = e/KNB;
  int j = nbr[e];
  float h[32];
  #pragma unroll
  for(int o=0;o<32;o++) h[o]=0.f;
  float f[32];
  load32(f, xl + (size_t)j*128);
  #pragma unroll
  for(int c=0;c<32;c++){
    const float* w = w1 + c*32;
    #pragma unroll
    for(int o=0;o<32;o++) h[o] += f[c]*w[o];
  }
  load32(f, xl + (size_t)n*128);
  #pragma unroll
  for(int c=0;c<32;c++){
    const float* w = w1 + (32+c)*32;
    #pragma unroll
    for(int o=0;o<32;o++) h[o] += f[c]*w[o];
  }
  load32(f, ef + (size_t)e*32);
  #pragma unroll
  for(int c=0;c<32;c++){
    const float* w = w1 + (64+c)*32;
    #pragma unroll
    for(int o=0;o<32;o++) h[o] += f[c]*w[o];
  }
  float acc[8];
  #pragma unroll
  for(int t=0;t<8;t++) acc[t]=0.f;
  #pragma unroll
  for(int o=0;o<32;o++){
    float v = siluf(h[o]);
    const float* w = w2 + o*8;
    #pragma unroll
    for(int t=0;t<8;t++) acc[t] += v*w[t];
  }
  float4* lg4 = (float4*)(logits + (size_t)e*8);
  lg4[0] = make_float4(acc[0],acc[1],acc[2],acc[3]);
  lg4[1] = make_float4(acc[4],acc[5],acc[6],acc[7]);
}

// ---------------- K7: softmax + aggregate (float4 gather) + o_w + FFN + fused norm ----------------
__global__ __launch_bounds__(256) void k_update(const int* __restrict__ nbr, const float* __restrict__ xl,
                         const float* __restrict__ logits, float* __restrict__ x,
                         float* __restrict__ xlout,
                         const float* __restrict__ vw, const float* __restrict__ ow,
                         const float* __restrict__ fw1, const float* __restrict__ fw2,
                         const float* __restrict__ fwg, const float* __restrict__ fv1,
                         const float* __restrict__ g0, const float* __restrict__ b0,
                         const float* __restrict__ g1){
  __shared__ float S_lg[4][240], S_m[4][8], S_inv[4][8];
  __shared__ float S_S[4][1024], S_agg[4][512], S_x[4][128];
  __shared__ float S_h[4][64], S_g[4][32], S_d0[4][32];
  int g = threadIdx.x>>6, t = threadIdx.x&63;
  int n = blockIdx.x*4 + g;
  for(int r=t; r<240; r+=64) S_lg[g][r] = logits[(size_t)n*240+r];
  if(t<8){
    float m=-1e30f;
    for(int kk=0;kk<KNB;kk++) m=fmaxf(m, S_lg[g][kk*8+t]);
    float s=0.f;
    for(int kk=0;kk<KNB;kk++) s += __expf(S_lg[g][kk*8+t]-m);
    S_m[g][t]=m; S_inv[g][t]=1.0f/s;
  }
  for(int r=t; r<240; r+=64){ int h=r&7; S_lg[g][r]=__expf(S_lg[g][r]-S_m[g][h])*S_inv[g][h]; }
  int hd = t>>3, i8 = t&7;
  const float4* xl4 = (const float4*)xl;
  float acc[16];
  for(int m=0;m<16;m++) acc[m]=0.f;
  for(int kk=0;kk<KNB;kk++){
    int j=nbr[n*KNB+kk];
    float a = S_lg[g][kk*8+hd];
    float4 b0v = xl4[j*32 + i8*4 + 0];
    float4 b1v = xl4[j*32 + i8*4 + 1];
    float4 b2v = xl4[j*32 + i8*4 + 2];
    float4 b3v = xl4[j*32 + i8*4 + 3];
    acc[0]+=a*b0v.x; acc[1]+=a*b0v.y; acc[2]+=a*b0v.z; acc[3]+=a*b0v.w;
    acc[4]+=a*b1v.x; acc[5]+=a*b1v.y; acc[6]+=a*b1v.z; acc[7]+=a*b1v.w;
    acc[8]+=a*b2v.x; acc[9]+=a*b2v.y; acc[10]+=a*b2v.z; acc[11]+=a*b2v.w;
    acc[12]+=a*b3v.x; acc[13]+=a*b3v.y; acc[14]+=a*b3v.z; acc[15]+=a*b3v.w;
  }
  for(int m=0;m<16;m++) S_S[g][hd*128 + i8*16 + m] = acc[m];
  for(int half=0; half<2; half++){
    int hv = half*64+t;
    int hh = hv>>4;
    float a0=0.f,a1=0.f,a2=0.f,a3=0.f;
    for(int c=0;c<32;c++){
      float w = vw[c*128+hv];
      a0 += S_S[g][hh*128 + c]*w;
      a1 += S_S[g][hh*128 + 32+c]*w;
      a2 += S_S[g][hh*128 + 64+c]*w;
      a3 += S_S[g][hh*128 + 96+c]*w;
    }
    S_agg[g][hv]=a0; S_agg[g][128+hv]=a1; S_agg[g][256+hv]=a2; S_agg[g][384+hv]=a3;
  }
  for(int half=0; half<2; half++){
    int e = half*64+t;
    int rrow = e>>5, c = e&31;
    float v = x[n*128+e];
    for(int hv=0;hv<128;hv++) v += S_agg[g][rrow*128+hv]*ow[hv*32+c];
    S_x[g][e]=v;
  }
  {
    float hs=0.f;
    for(int c=0;c<32;c++) hs += S_x[g][c]*fw1[c*64+t];
    S_h[g][t]=siluf(hs);
  }
  if(t<32){
    float gs=0.f, d0=0.f;
    for(int c=0;c<64;c++){ float hv=S_h[g][c]; gs += hv*fwg[c*32+t]; d0 += hv*fw2[c*32+t]; }
    S_g[g][t]=1.0f/(1.0f+__expf(-gs));
    S_d0[g][t]=d0;
  }
  for(int half=0; half<2; half++){
    int e = half*64+t;
    int rrow = e>>5, c = e&31;
    float xv = S_x[g][e], outv;
    if(rrow==0){ outv = xv + S_d0[g][c]; }
    else {
      float dv=0.f;
      for(int cc=0;cc<32;cc++) dv += S_x[g][rrow*32+cc]*fv1[cc*32+c];
      outv = xv + dv*S_g[g][c];
    }
    S_x[g][e]=outv;
    x[n*128+e]=outv;
  }
  if(t<32){
    float x0=S_x[g][t];
    float s=x0, s2=x0*x0;
    for(int off=16; off>0; off>>=1){ s+=__shfl_xor(s,off,32); s2+=__shfl_xor(s2,off,32); }
    float mu=s*(1.0f/32.0f), var=s2*(1.0f/32.0f)-mu*mu;
    float y0=(x0-mu)*rsqrtf(var+1e-6f)*g0[t]+b0[t];
    float v1=S_x[g][32+t], v2=S_x[g][64+t], v3=S_x[g][96+t];
    float ss=v1*v1+v2*v2+v3*v3;
    for(int off=16; off>0; off>>=1) ss+=__shfl_xor(ss,off,32);
    float sc=rsqrtf(ss*(1.0f/96.0f)+1e-6f);
    float gg=g1[t];
    xlout[n*128+t]=y0; xlout[n*128+32+t]=v1*sc*gg;
    xlout[n*128+64+t]=v2*sc*gg; xlout[n*128+96+t]=v3*sc*gg;
  }
}

// ---------------- K8: edge update + (optional) next-layer logits, lane-per-edge ----------------
// feat rows: 0..31 ef, 32..63 x[j], 64..95 x[n]; ew1 (96x64), ew2 (64x32)
template<bool FUSE_LOGITS>
__global__ __launch_bounds__(256,4) void k_efup_t(const int* __restrict__ nbr, const float* __restrict__ x,
                       const float* __restrict__ ew1, const float* __restrict__ ew2,
                       float* __restrict__ ef,
                       const float* __restrict__ xlnext,
                       const float* __restrict__ aw1n, const float* __restrict__ aw2n,
                       float* __restrict__ logits){
  int e = blockIdx.x*256 + threadIdx.x;
  int n = e/KNB;
  int j = nbr[e];
  float h[64];
  #pragma unroll
  for(int o=0;o<64;o++) h[o]=0.f;
  float f[32];
  load32(f, ef + (size_t)e*32);
  #pragma unroll
  for(int c=0;c<32;c++){
    const float* w = ew1 + c*64;
    #pragma unroll
    for(int o=0;o<64;o++) h[o] += f[c]*w[o];
  }
  load32(f, x + (size_t)j*128);
  #pragma unroll
  for(int c=0;c<32;c++){
    const float* w = ew1 + (32+c)*64;
    #pragma unroll
    for(int o=0;o<64;o++) h[o] += f[c]*w[o];
  }
  load32(f, x + (size_t)n*128);
  #pragma unroll
  for(int c=0;c<32;c++){
    const float* w = ew1 + (64+c)*64;
    #pragma unroll
    for(int o=0;o<64;o++) h[o] += f[c]*w[o];
  }
  float acc[32];
  #pragma unroll
  for(int t=0;t<32;t++) acc[t]=0.f;
  #pragma unroll
  for(int o=0;o<64;o++){
    float v = siluf(h[o]);
    const float* w = ew2 + o*32;
    #pragma unroll
    for(int t=0;t<32;t++) acc[t] += v*w[t];
  }
  // reload ef (L1-hot), form new ef in f, write residual
  load32(f, ef + (size_t)e*32);
  #pragma unroll
  for(int t=0;t<32;t++) f[t] += acc[t];
  float4* e4 = (float4*)(ef + (size_t)e*32);
  #pragma unroll
  for(int q=0;q<8;q++)
    e4[q] = make_float4(f[q*4+0], f[q*4+1], f[q*4+2], f[q*4+3]);
  if(FUSE_LOGITS){
    // next-layer attention logits on (xlnext[j], xlnext[n], new ef) — same chunk order as standalone
    float h2[32];
    #pragma unroll
    for(int o=0;o<32;o++) h2[o]=0.f;
    float g2[32];
    load32(g2, xlnext + (size_t)j*128);
    #pragma unroll
    for(int c=0;c<32;c++){
      const float* w = aw1n + c*32;
      #pragma unroll
      for(int o=0;o<32;o++) h2[o] += g2[c]*w[o];
    }
    load32(g2, xlnext + (size_t)n*128);
    #pragma unroll
    for(int c=0;c<32;c++){
      const float* w = aw1n + (32+c)*32;
      #pragma unroll
      for(int o=0;o<32;o++) h2[o] += g2[c]*w[o];
    }
    #pragma unroll
    for(int c=0;c<32;c++){
      const float* w = aw1n + (64+c)*32;
      #pragma unroll
      for(int o=0;o<32;o++) h2[o] += f[c]*w[o];
    }
    float a8[8];
    #pragma unroll
    for(int t=0;t<8;t++) a8[t]=0.f;
    #pragma unroll
    for(int o=0;o<32;o++){
      float v = siluf(h2[o]);
      const float* w = aw2n + o*8;
      #pragma unroll
      for(int t=0;t<8;t++) a8[t] += v*w[t];
    }
    float4* lg4 = (float4*)(logits + (size_t)e*8);
    lg4[0] = make_float4(a8[0],a8[1],a8[2],a8[3]);
    lg4[1] = make_float4(a8[4],a8[5],a8[6],a8[7]);
  }
}

// ---------------- K9a: out radial MLP, lane-per-edge, all-register -> orad (E,32) ----------------
__global__ __launch_bounds__(256,4) void k_orad(const float* __restrict__ ef,
                      const float* __restrict__ orw1, const float* __restrict__ orw2,
                      float* __restrict__ orad){
  int e = blockIdx.x*256 + threadIdx.x;
  float f[32];
  load32(f, ef + (size_t)e*32);
  float h[64];
  #pragma unroll
  for(int o=0;o<64;o++) h[o]=0.f;
  #pragma unroll
  for(int c=0;c<32;c++){
    const float* w = orw1 + c*64;
    #pragma unroll
    for(int o=0;o<64;o++) h[o] += f[c]*w[o];
  }
  float acc[32];
  #pragma unroll
  for(int t=0;t<32;t++) acc[t]=0.f;
  #pragma unroll
  for(int o=0;o<64;o++){
    float v = siluf(h[o]);
    const float* w = orw2 + o*32;
    #pragma unroll
    for(int t=0;t<32;t++) acc[t] += v*w[t];
  }
  float4* r4 = (float4*)(orad + (size_t)e*32);
  #pragma unroll
  for(int q=0;q<8;q++) r4[q] = make_float4(acc[q*4],acc[q*4+1],acc[q*4+2],acc[q*4+3]);
}

// ---------------- K9: out gather + projection + fused seq head ----------------
__global__ __launch_bounds__(256) void k_out(const int* __restrict__ nbr, const float* __restrict__ orad,
                      const float* __restrict__ x,
                      const float* __restrict__ outw,
                      const float* __restrict__ sw1, const float* __restrict__ sb1,
                      const float* __restrict__ sw2, const float* __restrict__ sb2,
                      const float* __restrict__ sw3, const float* __restrict__ sb3,
                      float* __restrict__ out, float* __restrict__ outseq){
  __shared__ float msg[4][128];
  __shared__ float h1[4][64], h2[4][32], lgs[4][20];
  int g = threadIdx.x>>6, t = threadIdx.x&63;
  int n = blockIdx.x*4 + g;
  int t31 = t&31;
  float acc0=0.f, acc1=0.f;
  for(int kk=0;kk<KNB;kk++){
    int e=n*KNB+kk;
    int j=nbr[e];
    float rl = orad[(size_t)e*32 + t31];
    acc0 += x[j*128+t]*rl;
    acc1 += x[j*128+64+t]*rl;
  }
  msg[g][t]=acc0*(1.0f/KNB); msg[g][64+t]=acc1*(1.0f/KNB);
  for(int o=t;o<91;o+=64){
    for(int rrow=1;rrow<4;rrow++){
      float s=0.f;
      for(int c=0;c<32;c++) s += msg[g][rrow*32+c]*outw[c*91+o];
      out[(size_t)n*273 + o*3 + (rrow-1)] = s;
    }
  }
  {
    float s=0.f;
    for(int c=0;c<32;c++) s += x[n*128+c]*sw1[c*64+t];
    h1[g][t]=fmaxf(s+sb1[t],0.f);
  }
  if(t<32){
    float s=0.f;
    for(int c=0;c<64;c++) s += h1[g][c]*sw2[c*32+t];
    h2[g][t]=fmaxf(s+sb2[t],0.f);
  }
  if(t<20){
    float s=0.f;
    for(int c=0;c<32;c++) s += h2[g][c]*sw3[c*20+t];
    lgs[g][t]=s+sb3[t];
  }
  if(t<20){
    float m=-1e30f;
    for(int c=0;c<20;c++) m=fmaxf(m,lgs[g][c]);
    float se=0.f;
    for(int c=0;c<20;c++) se += __expf(lgs[g][c]-m);
    outseq[(size_t)n*20+t]=lgs[g][t]-m-logf(se);
  }
}

extern "C" void kernel_launch(void* const* d_in, const int* in_sizes, int n_in,
                              void* d_out, int out_size, void* d_ws, size_t ws_size,
                              hipStream_t stream) {
  const float* bb      = (const float*)d_in[0];
  const float* latent  = (const float*)d_in[1];
  const float* ln_g0   = (const float*)d_in[2];
  const float* ln_b0   = (const float*)d_in[3];
  const float* ln_g1   = (const float*)d_in[4];
  const float* bbw1    = (const float*)d_in[5];
  const float* bbw2    = (const float*)d_in[6];
  const float* bboutw  = (const float*)d_in[7];
  const float* latw1   = (const float*)d_in[8];
  const float* latw2   = (const float*)d_in[9];
  const float* latoutw = (const float*)d_in[10];
  const float* tg0     = (const float*)d_in[11];
  const float* tb0     = (const float*)d_in[12];
  const float* tg1     = (const float*)d_in[13];
  const float* aw1     = (const float*)d_in[14];
  const float* aw2     = (const float*)d_in[15];
  const float* vw      = (const float*)d_in[16];
  const float* ow      = (const float*)d_in[17];
  const float* fw1     = (const float*)d_in[18];
  const float* fw2     = (const float*)d_in[19];
  const float* fwg     = (const float*)d_in[20];
  const float* fv1     = (const float*)d_in[21];
  const float* ew1     = (const float*)d_in[22];
  const float* ew2     = (const float*)d_in[23];
  const float* orw1    = (const float*)d_in[24];
  const float* orw2    = (const float*)d_in[25];
  const float* outw    = (const float*)d_in[26];
  const float* sw1     = (const float*)d_in[27];
  const float* sb1     = (const float*)d_in[28];
  const float* sw2     = (const float*)d_in[29];
  const float* sb2     = (const float*)d_in[30];
  const float* sw3     = (const float*)d_in[31];
  const float* sb3     = (const float*)d_in[32];
  float* outp = (float*)d_out;

  // workspace layout (radbb overlays logits; orad overlays radlat)
  int*    nbr    = (int*)d_ws;
  float*  ef     = (float*)((char*)d_ws + 1024*1024);
  float*  xbuf   = ef   + (size_t)NEDGE*32;
  float*  xlA    = xbuf + (size_t)NRES*128;
  float*  xlB    = xlA  + (size_t)NRES*128;
  float*  bbf    = xlB  + (size_t)NRES*128;
  float*  logits = bbf  + (size_t)NRES*28;
  float4* ca     = (float4*)(logits + (size_t)NEDGE*8);
  float*  edgescratch = (float*)(ca + NRES);     // NEDGE*32 floats
  float*  radbb  = logits;                       // NEDGE*8, dead before first k_logits
  float*  radlat = edgescratch;                  // NEDGE*32, dead after k_init
  float*  orad   = edgescratch;                  // reused at the end

  k_bbfeat  <<<NRES/256, 256, 0, stream>>>(bb, bbf, ca);
  k_knn     <<<NRES/4,   256, 0, stream>>>(ca, nbr);
  k_edgefeat<<<NEDGE/256, 256, 0, stream>>>(ca, nbr, ef);
  k_norm    <<<NRES*32/256, 256, 0, stream>>>(latent, xlA, ln_g0, ln_b0, ln_g1);
  k_rad     <<<NEDGE/256, 256, 0, stream>>>(ef, bbw1, bbw2, latw1, latw2, radbb, radlat);
  k_init    <<<NRES/4, 256, 0, stream>>>(nbr, radbb, radlat, bbf, xlA,
                                         bboutw, latoutw,
                                         tg0, tb0, tg1,
                                         xbuf, xlB);
  // layer-0 logits standalone; layers 1..3 logits fused into k_efup of the previous layer
  k_logits<<<NEDGE/256, 256, 0, stream>>>(nbr, xlB, ef, aw1, aw2, logits);
  for(int l=0;l<4;l++){
    const float* xl_in  = (l&1) ? xlA : xlB;
    float*       xl_out = (l&1) ? xlB : xlA;
    int ln = (l+1<4) ? (l+1) : 3;
    k_update <<<NRES/4, 256, 0, stream>>>(nbr, xl_in, logits, xbuf, xl_out,
                                          vw+l*32*128, ow+l*128*32,
                                          fw1+l*32*64, fw2+l*64*32,
                                          fwg+l*64*32, fv1+l*32*32,
                                          tg0+ln*32, tb0+ln*32, tg1+ln*32);
    if(l<3)
      k_efup_t<true><<<NEDGE/256, 256, 0, stream>>>(nbr, xbuf, ew1+l*96*64, ew2+l*64*32, ef,
                                                    xl_out, aw1+(l+1)*96*32, aw2+(l+1)*32*8, logits);
    else
      k_efup_t<false><<<NEDGE/256, 256, 0, stream>>>(nbr, xbuf, ew1+l*96*64, ew2+l*64*32, ef,
                                                     nullptr, nullptr, nullptr, nullptr);
  }
  k_orad<<<NEDGE/256, 256, 0, stream>>>(ef, orw1, orw2, orad);
  k_out <<<NRES/4, 256, 0, stream>>>(nbr, orad, xbuf, outw,
                                     sw1, sb1, sw2, sb2, sw3, sb3,
                                     outp, outp + (size_t)NRES*273);
}